// Round 7
// baseline (465.368 us; speedup 1.0000x reference)
//
#include <hip/hip_runtime.h>
#include <stdint.h>

// Problem constants
#define B_  4096
#define D_  1024
#define R_  2048
#define MAXD 2560

typedef _Float16 half8 __attribute__((ext_vector_type(8)));  // 8 fp16 = 4 VGPRs (MFMA frag)
typedef _Float16 half4 __attribute__((ext_vector_type(4)));
typedef float    f32x4 __attribute__((ext_vector_type(4)));

constexpr int BM = 128;      // M tile (batch rows)
constexpr int BN = 64;       // N tile (reservoir cols)
constexpr int BK = 32;       // K chunk (elems)
constexpr int NCH1 = D_ / BK;   // 32 phase-1 chunks (X vs Win+gates)
constexpr int NCH2 = R_ / BK;   // 64 phase-2 chunks (prev vs Wres)

// ---- ws layout: W-ONLY MFMA-fragment chunks ------------------------------
// chunk(rowgrp, kb, pl) = 512 halves (1 KiB). halves[l*8 + j] =
//   plane_pl( W[rowgrp*16 + (l&15)][kb*32 + (l>>4)*8 + j] )
// pl=0: fp16 hi (RTN), pl=1: fp16 lo (residual). Exactly the 16x16x32 MFMA
// B lane mapping (verified rounds 0-6). Chunk-pair (pl0,pl1) adjacent.
// Round-7: X and P are NOT packed -- A is loaded fp32 and split in-register
// (A-conversion is per-block-private, not redundant; only W's was 32x).
constexpr size_t WIF_OFF = 0;                                   // Win: 128rg x 32kb
constexpr size_t WRF_OFF = WIF_OFF + (size_t)128 * 32 * 1024;   // Wres: 128rg x 64kb
constexpr size_t WGF_OFF = WRF_OFF + (size_t)128 * 64 * 1024;   // Wg: 384rg x 32kb
constexpr size_t WS_HALVES = WGF_OFF + (size_t)384 * 32 * 1024; // 25,165,824
constexpr size_t WS_BYTES  = WS_HALVES * 2;                     // 48 MiB
constexpr int NW_TASKS    = 4096 + 8192 + 12288;  // 24576 chunk-pair wave-tasks
constexpr int NPAD_WTASKS = 8192;                 // out[:,2048:2560] zero

// PRECISE activations (round-0-verified). Do NOT substitute fast approximations:
// the spike-subtract at 0.5 is a discontinuity -- any epsilon of extra numeric
// error flips elements across it for a 0.5-sized absmax (round-1 post-mortem).
__device__ __forceinline__ float sigmoidf_(float x) { return 1.0f / (1.0f + expf(-x)); }

// global -> LDS DMA, 16 B per lane. LDS dest is wave-uniform base + lane*16 (HW);
// global src is per-lane.
__device__ __forceinline__ void gload_lds16(const _Float16* g, _Float16* l) {
    typedef const uint32_t __attribute__((address_space(1)))* gp_t;
    typedef uint32_t __attribute__((address_space(3)))* lp_t;
    __builtin_amdgcn_global_load_lds((gp_t)(const void*)g, (lp_t)(void*)l, 16, 0, 0);
}

// ---- prep: repack WEIGHTS into hi/lo fragment chunks + pad-zero ----------
// One wave per chunk-pair: lane reads 8 consecutive fp32 (32 B), RTN-splits
// (bit-identical to rounds 0-6), writes hi 16 B + lo 16 B, coalesced.
// Traffic: 48 MB read + 48 MB write + 16 MB pad (was ~230 MB in r3-r6).
__global__ __launch_bounds__(256)
void prep(const float* __restrict__ Win, const float* __restrict__ Wres,
          const float* __restrict__ Wg, _Float16* __restrict__ ws,
          float* __restrict__ out)
{
    const int l = threadIdx.x & 63;
    const int wtask = blockIdx.x * 4 + (threadIdx.x >> 6);
    if (wtask < NW_TASKS) {
        const float* src; int ld, rg, kb;
        int cp = wtask;
        if (cp < 4096)       {              src = Win;  ld = D_; rg = cp >> 5; kb = cp & 31; }
        else if (cp < 12288) { cp -= 4096;  src = Wres; ld = R_; rg = cp >> 6; kb = cp & 63; }
        else                 { cp -= 12288; src = Wg;   ld = D_; rg = cp >> 5; kb = cp & 31; }
        const float* s = src + (size_t)(rg * 16 + (l & 15)) * ld + kb * 32 + (l >> 4) * 8;
        f32x4 v0 = *(const f32x4*)s;
        f32x4 v1 = *(const f32x4*)(s + 4);
        half8 h, lo;
        #pragma unroll
        for (int j = 0; j < 4; ++j) {
            h[j]     = (_Float16)v0[j];  lo[j]     = (_Float16)(v0[j] - (float)h[j]);
            h[4 + j] = (_Float16)v1[j];  lo[4 + j] = (_Float16)(v1[j] - (float)h[4 + j]);
        }
        _Float16* dst = ws + (size_t)wtask * 1024;
        *(half8*)(dst + l * 8) = h;          // pl 0
        *(half8*)(dst + 512 + l * 8) = lo;   // pl 1
    } else {
        int p2 = wtask - NW_TASKS;                     // 0..8191
        size_t idx = (size_t)p2 * 256 + l * 4;         // over 4096 x 512 pad region
        size_t row = idx >> 9, col = idx & 511;
        *(f32x4*)(out + row * MAXD + R_ + col) = (f32x4){0.f, 0.f, 0.f, 0.f};
    }
}

// ---- main fused kernel (packed-W path) -----------------------------------
// pre = X*Win^T + prev*Wres^T (K=3072), gates = X*Wgate^T (K=1024, 3 sets),
// state = o*( 0.9*f*prev + 0.1*tanh(i*pre) ), spike-subtract, fp32 store.
// 3-term fp16 split (hh+lh+hl), state error ~1e-7, zero threshold-flips.
//
// Structure (r6-verified + r7 A-path): A loaded as raw fp32 dwordx4 per lane
// (fragment addressing), hi/lo split IN-REGISTER at the top of each MFMA
// block (VALU pipe, overlaps MFMA per m114); W staged via global_load_lds DMA
// into double-buffered 64 KiB LDS (bank-conflict-free, r6: conflicts == 0).
// ONE barrier per chunk, counted `s_waitcnt vmcnt(4)`: issue order per chunk
// is [W DMAs (8 ph1 / 2 ph2)] -> fence -> [4 A dwordx4]; waiting to <=4
// outstanding drains exactly the W DMAs (oldest-first, m135); A loads stay in
// flight and are waited at the cvt by compiler waitcnt.
__global__ __launch_bounds__(256, 2)
void reservoir_packed(const float* __restrict__ X,      // B x D fp32
                      const float* __restrict__ P,      // B x MAXD fp32
                      const _Float16* __restrict__ ws,  // packed W planes
                      float* __restrict__ out)          // B x MAXD
{
    __shared__ _Float16 smem[32768];                    // 2 bufs x 16384 halves (64 KiB)

    const int tid  = threadIdx.x;
    const int lane = tid & 63;
    const int wv   = tid >> 6;                          // wave id 0..3
    const int m0   = blockIdx.y * BM;
    const int n0   = blockIdx.x * BN;
    const int lb   = lane * 8;                          // lane offset within chunk (halves)
    const int rgA  = (m0 >> 4) + wv * 2;                // this wave's A rowgroup base
    const int ng0  = n0 >> 4;                           // block's W colgroup base

    f32x4 acc[4][2][4];                                 // [set][mtile][ntile]
    #pragma unroll
    for (int s = 0; s < 4; ++s)
        #pragma unroll
        for (int mt = 0; mt < 2; ++mt)
            #pragma unroll
            for (int nt = 0; nt < 4; ++nt) acc[s][mt][nt] = (f32x4){0.f, 0.f, 0.f, 0.f};

    // W DMA: ph1 stages 32 KiB (32 chunks: 4 sets x 4 grps x 2 planes), 8/wave.
    // LDS layout per buffer: pl*8192 + (s*4+g)*512.
    auto dmaW1 = [&](int t, int buf) {
        #pragma unroll
        for (int i = 0; i < 8; ++i) {
            const int c = wv * 8 + i, pl = c >> 4, r = c & 15, s = r >> 2, g = r & 3;
            const size_t gh = (s == 0)
                ? WIF_OFF + ((size_t)((ng0 + g) * 32 + t) * 2 + pl) * 512
                : WGF_OFF + ((size_t)(((s - 1) * 128 + ng0 + g) * 32 + t) * 2 + pl) * 512;
            gload_lds16(ws + gh + lb, &smem[buf * 16384 + pl * 8192 + r * 512]);
        }
    };
    // ph2 stages 8 KiB (1 set x 4 grps x 2 planes), 2/wave.
    auto dmaW2 = [&](int t, int buf) {
        #pragma unroll
        for (int i = 0; i < 2; ++i) {
            const int c = wv * 2 + i, pl = c >> 2, g = c & 3;
            const size_t gh = WRF_OFF + ((size_t)((ng0 + g) * 64 + t) * 2 + pl) * 512;
            gload_lds16(ws + gh + lb, &smem[buf * 16384 + pl * 8192 + g * 512]);
        }
    };

    // A fragment addressing: lane l covers rows rgA*16+(l&15) (+16 for frag 1),
    // k = t*32 + (l>>4)*8 .. +7 -> two f32x4 per frag, 4 dwordx4 loads per chunk.
    const float* aX = X + (size_t)(rgA * 16 + (lane & 15)) * D_   + (lane >> 4) * 8;
    const float* aP = P + (size_t)(rgA * 16 + (lane & 15)) * MAXD + (lane >> 4) * 8;

// Raw A loads: named regs only (rule #20 -- no runtime-indexed reg arrays).
#define LDA_RAW(BASE, LD16, T, V0, V1, V2, V3)                                                    \
    {                                                                                             \
        const float* p_ = (BASE) + (size_t)(T) * BK;                                              \
        V0 = *(const f32x4*)p_;             V1 = *(const f32x4*)(p_ + 4);                         \
        V2 = *(const f32x4*)(p_ + (LD16));  V3 = *(const f32x4*)(p_ + (LD16) + 4);                \
    }

// MFMA block: in-register hi/lo split of raw A (bit-identical RTN ops to
// rounds 0-6), W frags from smem[BB..].
#define MBLK(BB, NSETS, V0, V1, V2, V3)                                                           \
    {                                                                                             \
        half8 ah0, al0, ah1, al1;                                                                 \
        _Pragma("unroll")                                                                         \
        for (int j = 0; j < 4; ++j) {                                                             \
            ah0[j]     = (_Float16)V0[j];  al0[j]     = (_Float16)(V0[j] - (float)ah0[j]);        \
            ah0[4 + j] = (_Float16)V1[j];  al0[4 + j] = (_Float16)(V1[j] - (float)ah0[4 + j]);    \
            ah1[j]     = (_Float16)V2[j];  al1[j]     = (_Float16)(V2[j] - (float)ah1[j]);        \
            ah1[4 + j] = (_Float16)V3[j];  al1[4 + j] = (_Float16)(V3[j] - (float)ah1[4 + j]);    \
        }                                                                                         \
        __builtin_amdgcn_s_setprio(1);                                                            \
        _Pragma("unroll")                                                                         \
        for (int s = 0; s < (NSETS); ++s) {                                                       \
            _Pragma("unroll")                                                                     \
            for (int nt = 0; nt < 4; ++nt) {                                                      \
                half8 bh = *(const half8*)&smem[(BB) + (s * 4 + nt) * 512 + lb];                  \
                half8 bl = *(const half8*)&smem[(BB) + 8192 + (s * 4 + nt) * 512 + lb];           \
                acc[s][0][nt] = __builtin_amdgcn_mfma_f32_16x16x32_f16(ah0, bh, acc[s][0][nt], 0, 0, 0); \
                acc[s][0][nt] = __builtin_amdgcn_mfma_f32_16x16x32_f16(al0, bh, acc[s][0][nt], 0, 0, 0); \
                acc[s][0][nt] = __builtin_amdgcn_mfma_f32_16x16x32_f16(ah0, bl, acc[s][0][nt], 0, 0, 0); \
                acc[s][1][nt] = __builtin_amdgcn_mfma_f32_16x16x32_f16(ah1, bh, acc[s][1][nt], 0, 0, 0); \
                acc[s][1][nt] = __builtin_amdgcn_mfma_f32_16x16x32_f16(al1, bh, acc[s][1][nt], 0, 0, 0); \
                acc[s][1][nt] = __builtin_amdgcn_mfma_f32_16x16x32_f16(ah1, bl, acc[s][1][nt], 0, 0, 0); \
            }                                                                                     \
        }                                                                                         \
        __builtin_amdgcn_s_setprio(0);                                                            \
    }

// Counted-vmcnt barrier: the 4 A loads issued after the W DMAs may remain in
// flight; all W DMAs must have landed. lgkmcnt(0) drains this wave's ds_reads
// (cross-wave WAR safety for the buffer the next DMA overwrites).
#define BARR()                                                                                    \
    {                                                                                             \
        __builtin_amdgcn_sched_barrier(0);                                                        \
        asm volatile("s_waitcnt vmcnt(4) lgkmcnt(0)" ::: "memory");                               \
        __builtin_amdgcn_s_barrier();                                                             \
        __builtin_amdgcn_sched_barrier(0);                                                        \
    }
#define FENCE() __builtin_amdgcn_sched_barrier(0)

    f32x4 xa0, xa1, xa2, xa3, xb0, xb1, xb2, xb3;

    // prologue: chunk 0 -> buf0 / raw A regs
    dmaW1(0, 0);
    FENCE();
    LDA_RAW(aX, 16 * D_, 0, xa0, xa1, xa2, xa3);
    BARR();

    // ---- Phase 1: X vs {Win, gates}; chunks 0..31, unroll-by-2 for parity
    #pragma unroll 1
    for (int t = 0; t < NCH1 - 2; t += 2) {
        dmaW1(t + 1, 1); FENCE(); LDA_RAW(aX, 16 * D_, t + 1, xb0, xb1, xb2, xb3);
        MBLK(0, 4, xa0, xa1, xa2, xa3)
        BARR();
        dmaW1(t + 2, 0); FENCE(); LDA_RAW(aX, 16 * D_, t + 2, xa0, xa1, xa2, xa3);
        MBLK(16384, 4, xb0, xb1, xb2, xb3)
        BARR();
    }
    // t=30: prefetch 31 (ph1); t=31: prefetch ph2 chunk 0
    dmaW1(31, 1); FENCE(); LDA_RAW(aX, 16 * D_, 31, xb0, xb1, xb2, xb3);
    MBLK(0, 4, xa0, xa1, xa2, xa3)
    BARR();
    dmaW2(0, 0); FENCE(); LDA_RAW(aP, 16 * MAXD, 0, xa0, xa1, xa2, xa3);
    MBLK(16384, 4, xb0, xb1, xb2, xb3)
    BARR();

    // ---- Phase 2: prev vs Wres; chunks 0..63 (chunk t lives in buf[t&1])
    #pragma unroll 1
    for (int t = 0; t < NCH2 - 2; t += 2) {
        dmaW2(t + 1, 1); FENCE(); LDA_RAW(aP, 16 * MAXD, t + 1, xb0, xb1, xb2, xb3);
        MBLK(0, 1, xa0, xa1, xa2, xa3)
        BARR();
        dmaW2(t + 2, 0); FENCE(); LDA_RAW(aP, 16 * MAXD, t + 2, xa0, xa1, xa2, xa3);
        MBLK(16384, 1, xb0, xb1, xb2, xb3)
        BARR();
    }
    // t=62: prefetch 63; t=63: no prefetch, no trailing barrier
    dmaW2(63, 1); FENCE(); LDA_RAW(aP, 16 * MAXD, 63, xb0, xb1, xb2, xb3);
    MBLK(0, 1, xa0, xa1, xa2, xa3)
    BARR();
    MBLK(16384, 1, xb0, xb1, xb2, xb3)

#undef MBLK
#undef LDA_RAW
#undef BARR
#undef FENCE

    // ---- epilogue: C/D layout col=lane&15, row=quad*4+reg (m89-verified) ----
    const int fr = lane & 15;
    const int qd = lane >> 4;
    #pragma unroll
    for (int mt = 0; mt < 2; ++mt)
        #pragma unroll
        for (int nt = 0; nt < 4; ++nt)
            #pragma unroll
            for (int r = 0; r < 4; ++r) {
                int row = m0 + wv * 32 + mt * 16 + qd * 4 + r;   // batch index
                int col = n0 + nt * 16 + fr;                      // reservoir index
                float pre = acc[0][mt][nt][r];
                float ig  = sigmoidf_(acc[1][mt][nt][r]);
                float fg  = sigmoidf_(acc[2][mt][nt][r]);
                float og  = sigmoidf_(acc[3][mt][nt][r]);
                float pv  = P[(size_t)row * MAXD + col];          // exact fp32 prev
                float st  = 0.9f * (fg * pv) + 0.1f * tanhf(ig * pre);
                st *= og;
                if (st > 0.5f) st -= 0.5f;
                out[(size_t)row * MAXD + col] = st;
            }
}

// =================== fallback path (no/short workspace) =====================
// Round-2 kernel verbatim (passed at 351 us standalone).
__device__ __forceinline__ void wg_barrier_ref() {
    __builtin_amdgcn_sched_barrier(0);
    asm volatile("s_waitcnt lgkmcnt(0)" ::: "memory");
    __builtin_amdgcn_s_barrier();
    __builtin_amdgcn_sched_barrier(0);
}

__global__ __launch_bounds__(256, 2)
void reservoir_ref(const float* __restrict__ X, const float* __restrict__ P,
                   const float* __restrict__ Win, const float* __restrict__ Wres,
                   const float* __restrict__ Wg, float* __restrict__ out)
{
    __shared__ _Float16 sA[2][8][512];
    __shared__ _Float16 sW[2][4][4][512];
    const int tid  = threadIdx.x;
    const int lane = tid & 63;
    const int wv   = tid >> 6;
    const int m0   = blockIdx.y * BM;
    const int n0   = blockIdx.x * BN;
    f32x4 acc[4][2][4];
    #pragma unroll
    for (int s = 0; s < 4; ++s)
        #pragma unroll
        for (int mt = 0; mt < 2; ++mt)
            #pragma unroll
            for (int nt = 0; nt < 4; ++nt) acc[s][mt][nt] = (f32x4){0.f, 0.f, 0.f, 0.f};
    const int crow = tid >> 3;
    const int c4   = (tid & 7) * 4;
    const int q    = c4 >> 3;
    const int fbase = q * 128 + (c4 & 4);
    const int raddr = ((((lane & 15) ^ (lane >> 4)) << 3) + ((lane >> 4) << 7));
    f32x4 pa[4];
    f32x4 pw[8];
    auto issue_loads = [&](int t) {
        if (t < NCH1) {
            const int kc = t * BK + c4;
            const float* a = X + (size_t)m0 * D_ + kc;
            #pragma unroll
            for (int i = 0; i < 4; ++i) pa[i] = *(const f32x4*)(a + (size_t)(crow + 32 * i) * D_);
            const float* w = Win + (size_t)n0 * D_ + kc;
            #pragma unroll
            for (int i = 0; i < 2; ++i) pw[i] = *(const f32x4*)(w + (size_t)(crow + 32 * i) * D_);
            const float* g = Wg + (size_t)n0 * D_ + kc;
            #pragma unroll
            for (int gg = 0; gg < 3; ++gg)
                #pragma unroll
                for (int i = 0; i < 2; ++i)
                    pw[2 + gg * 2 + i] = *(const f32x4*)(g + (size_t)(gg * R_ + crow + 32 * i) * D_);
        } else {
            const int kc = t * BK - D_ + c4;
            const float* a = P + (size_t)m0 * MAXD + kc;
            #pragma unroll
            for (int i = 0; i < 4; ++i) pa[i] = *(const f32x4*)(a + (size_t)(crow + 32 * i) * MAXD);
            const float* w = Wres + (size_t)n0 * R_ + kc;
            #pragma unroll
            for (int i = 0; i < 2; ++i) pw[i] = *(const f32x4*)(w + (size_t)(crow + 32 * i) * R_);
        }
    };
    auto stage_A = [&]() {
        #pragma unroll
        for (int i = 0; i < 4; ++i) {
            const int r = crow + 32 * i;
            const int idx = (((r & 15) ^ q) << 3) + fbase;
            half4 h, l;
            #pragma unroll
            for (int j = 0; j < 4; ++j) {
                float v = pa[i][j];
                h[j] = (_Float16)v;
                l[j] = (_Float16)(v - (float)h[j]);
            }
            *(half4*)(&sA[0][r >> 4][idx]) = h;
            *(half4*)(&sA[1][r >> 4][idx]) = l;
        }
    };
    auto stage_W = [&](int nw) {
        #pragma unroll
        for (int i = 0; i < 8; ++i) if (i < nw) {
            const int s   = (i < 2) ? 0 : 1 + ((i - 2) >> 1);
            const int sub = (i < 2) ? i : ((i - 2) & 1);
            const int r   = crow + 32 * sub;
            const int idx = (((r & 15) ^ q) << 3) + fbase;
            half4 h, l;
            #pragma unroll
            for (int j = 0; j < 4; ++j) {
                float v = pw[i][j];
                h[j] = (_Float16)v;
                l[j] = (_Float16)(v - (float)h[j]);
            }
            *(half4*)(&sW[0][s][r >> 4][idx]) = h;
            *(half4*)(&sW[1][s][r >> 4][idx]) = l;
        }
    };
#define RMFMA(NSETS)                                                                              \
    {                                                                                             \
        half8 ah0 = *(const half8*)(&sA[0][wv * 2 + 0][raddr]);                                   \
        half8 al0 = *(const half8*)(&sA[1][wv * 2 + 0][raddr]);                                   \
        half8 ah1 = *(const half8*)(&sA[0][wv * 2 + 1][raddr]);                                   \
        half8 al1 = *(const half8*)(&sA[1][wv * 2 + 1][raddr]);                                   \
        _Pragma("unroll")                                                                         \
        for (int s = 0; s < NSETS; ++s) {                                                         \
            _Pragma("unroll")                                                                     \
            for (int nt = 0; nt < 4; ++nt) {                                                      \
                half8 bh = *(const half8*)(&sW[0][s][nt][raddr]);                                 \
                half8 bl = *(const half8*)(&sW[1][s][nt][raddr]);                                 \
                acc[s][0][nt] = __builtin_amdgcn_mfma_f32_16x16x32_f16(ah0, bh, acc[s][0][nt], 0, 0, 0); \
                acc[s][0][nt] = __builtin_amdgcn_mfma_f32_16x16x32_f16(al0, bh, acc[s][0][nt], 0, 0, 0); \
                acc[s][0][nt] = __builtin_amdgcn_mfma_f32_16x16x32_f16(ah0, bl, acc[s][0][nt], 0, 0, 0); \
                acc[s][1][nt] = __builtin_amdgcn_mfma_f32_16x16x32_f16(ah1, bh, acc[s][1][nt], 0, 0, 0); \
                acc[s][1][nt] = __builtin_amdgcn_mfma_f32_16x16x32_f16(al1, bh, acc[s][1][nt], 0, 0, 0); \
                acc[s][1][nt] = __builtin_amdgcn_mfma_f32_16x16x32_f16(ah1, bl, acc[s][1][nt], 0, 0, 0); \
            }                                                                                     \
        }                                                                                         \
    }
    issue_loads(0);
    #pragma unroll 1
    for (int t = 0; t < NCH1; ++t) {
        stage_A(); stage_W(8);
        issue_loads(t + 1);
        wg_barrier_ref();
        RMFMA(4)
        wg_barrier_ref();
    }
    #pragma unroll 1
    for (int t = NCH1; t < NCH1 + NCH2; ++t) {
        stage_A(); stage_W(2);
        if (t + 1 < NCH1 + NCH2) issue_loads(t + 1);
        wg_barrier_ref();
        RMFMA(1)
        wg_barrier_ref();
    }
#undef RMFMA
    const int fr = lane & 15;
    const int qd = lane >> 4;
    #pragma unroll
    for (int mt = 0; mt < 2; ++mt)
        #pragma unroll
        for (int nt = 0; nt < 4; ++nt)
            #pragma unroll
            for (int r = 0; r < 4; ++r) {
                int row = m0 + wv * 32 + mt * 16 + qd * 4 + r;
                int col = n0 + nt * 16 + fr;
                float pre = acc[0][mt][nt][r];
                float ig  = sigmoidf_(acc[1][mt][nt][r]);
                float fg  = sigmoidf_(acc[2][mt][nt][r]);
                float og  = sigmoidf_(acc[3][mt][nt][r]);
                float pv  = P[(size_t)row * MAXD + col];
                float st  = 0.9f * (fg * pv) + 0.1f * tanhf(ig * pre);
                st *= og;
                if (st > 0.5f) st -= 0.5f;
                out[(size_t)row * MAXD + col] = st;
            }
}

__global__ void pad_zero(float* __restrict__ out) {
    int idx = blockIdx.x * 256 + threadIdx.x;
    int row = idx >> 7;
    int c   = (idx & 127) * 4;
    *(f32x4*)(&out[(size_t)row * MAXD + R_ + c]) = (f32x4){0.f, 0.f, 0.f, 0.f};
}

extern "C" void kernel_launch(void* const* d_in, const int* in_sizes, int n_in,
                              void* d_out, int out_size, void* d_ws, size_t ws_size,
                              hipStream_t stream) {
    const float* X    = (const float*)d_in[0];
    const float* P    = (const float*)d_in[1];
    const float* Win  = (const float*)d_in[2];
    const float* Wres = (const float*)d_in[3];
    const float* Wg   = (const float*)d_in[4];
    float* out        = (float*)d_out;

    dim3 grid(R_ / BN, B_ / BM);   // (32, 32) = 1024 blocks

    if (d_ws != nullptr && ws_size >= WS_BYTES) {
        _Float16* ws = (_Float16*)d_ws;
        prep<<<(NW_TASKS + NPAD_WTASKS) / 4, 256, 0, stream>>>(Win, Wres, Wg, ws, out);
        reservoir_packed<<<grid, 256, 0, stream>>>(X, P, (const _Float16*)ws, out);
    } else {
        pad_zero<<<2048, 256, 0, stream>>>(out);
        reservoir_ref<<<grid, 256, 0, stream>>>(X, P, Win, Wres, Wg, out);
    }
}